// Round 12
// baseline (533.565 us; speedup 1.0000x reference)
//
#include <hip/hip_runtime.h>

typedef unsigned short u16;
typedef __attribute__((ext_vector_type(4))) float f32x4;
typedef __attribute__((ext_vector_type(8))) short bf16x8;
typedef __attribute__((ext_vector_type(8))) unsigned short u16x8;
typedef __attribute__((ext_vector_type(4))) unsigned short u16x4;

__device__ __forceinline__ u16 f2bf(float f) {
  union { float f; unsigned u; } v; v.f = f;
  unsigned r = v.u + 0x7FFFu + ((v.u >> 16) & 1u);
  return (u16)(r >> 16);
}
__device__ __forceinline__ float bf2f(u16 h) {
  union { unsigned u; float f; } v; v.u = ((unsigned)h) << 16; return v.f;
}

__device__ __forceinline__ void gload_lds16(const void* g, void* l) {
  __builtin_amdgcn_global_load_lds((const __attribute__((address_space(1))) void*)g,
                                   (__attribute__((address_space(3))) void*)l, 16, 0, 0);
}

// ---------------- prep kernels ----------------

__global__ void k_zero(u16x8* __restrict__ p, int n8) {
  int i = blockIdx.x * blockDim.x + threadIdx.x;
  int stride = gridDim.x * blockDim.x;
  u16x8 z = (u16x8)0;
  for (; i < n8; i += stride) p[i] = z;
}

__global__ void k_cvt_x(const float* __restrict__ in, u16* __restrict__ out, int n4) {
  int i = blockIdx.x * blockDim.x + threadIdx.x;
  int stride = gridDim.x * blockDim.x;
  const f32x4* in4 = (const f32x4*)in;
  u16x4* out4 = (u16x4*)out;
  for (; i < n4; i += stride) {
    f32x4 v = in4[i];
    u16x4 o;
    o[0] = f2bf(v[0]); o[1] = f2bf(v[1]); o[2] = f2bf(v[2]); o[3] = f2bf(v[3]);
    out4[i] = o;
  }
}

// LDS-tiled transpose: w [K][1024] f32 -> outT [1024][K] bf16, 64x64 tiles.
__global__ void k_prep_wt(const float* __restrict__ wq, const float* __restrict__ wo,
                          const float* __restrict__ wk, const float* __restrict__ wv,
                          u16* __restrict__ WQ1T, u16* __restrict__ WO1T,
                          u16* __restrict__ WK1T, u16* __restrict__ WV1T) {
  __shared__ u16 tile[64][72];
  int bid = blockIdx.x;
  const float* w; u16* o; int K;
  if (bid < 256)      { w = wq; o = WQ1T; K = 1024; }
  else if (bid < 512) { w = wo; o = WO1T; K = 1024; bid -= 256; }
  else if (bid < 704) { w = wk; o = WK1T; K = 768;  bid -= 512; }
  else                { w = wv; o = WV1T; K = 768;  bid -= 704; }
  const int ti = bid >> 4, tj = bid & 15;
  const int t = threadIdx.x;
  const int r = t >> 2, cq = (t & 3) * 16;

  const float* src = w + (size_t)(ti * 64 + r) * 1024 + tj * 64 + cq;
#pragma unroll
  for (int j4 = 0; j4 < 4; ++j4) {
    f32x4 v = *(const f32x4*)(src + j4 * 4);
#pragma unroll
    for (int e = 0; e < 4; ++e) tile[r][cq + j4 * 4 + e] = f2bf(v[e]);
  }
  __syncthreads();

  u16 vals[16];
#pragma unroll
  for (int j = 0; j < 16; ++j) vals[j] = tile[cq + j][r];
  u16* dst = o + (size_t)(tj * 64 + r) * K + ti * 64 + cq;
  *(u16x8*)dst = *(u16x8*)&vals[0];
  *(u16x8*)(dst + 8) = *(u16x8*)&vals[8];
}

// y [1232][768] f32 -> yb bf16 (straight cvt)
__global__ void k_prep_y(const float* __restrict__ y, u16* __restrict__ yb, int n4) {
  int i = blockIdx.x * blockDim.x + threadIdx.x;
  int stride = gridDim.x * blockDim.x;
  const f32x4* in4 = (const f32x4*)y;
  u16x4* out4 = (u16x4*)yb;
  for (; i < n4; i += stride) {
    f32x4 v = in4[i];
    u16x4 o;
    o[0] = f2bf(v[0]); o[1] = f2bf(v[1]); o[2] = f2bf(v[2]); o[3] = f2bf(v[3]);
    out4[i] = o;
  }
}

// ---------------- K+V projections, merged, m97-style 128^2 ----------------
__global__ __launch_bounds__(256, 2) void k_gemm_kv(
    const u16* __restrict__ A,
    const u16* __restrict__ BK1, const float* __restrict__ bkb, u16* __restrict__ KTo,
    const u16* __restrict__ BV1, const float* __restrict__ bvb, u16* __restrict__ VTo)
{
  const int M = 1232, Kdim = 768;
  __shared__ u16 sA[128 * 32];
  __shared__ u16 sB[128 * 32];
  const int t = threadIdx.x;
  const int half = blockIdx.x >= 80;
  const int bb = blockIdx.x - half * 80;
  const u16* B = half ? BV1 : BK1;
  const float* bias = half ? bvb : bkb;
  u16* outp = half ? VTo : KTo;
  const int bm = bb / 8, bn = bb % 8;
  const int m0 = bm * 128, n0 = bn * 128;
  const int l = t & 63, wv_ = t >> 6;
  const int lr = l & 15, lg = l >> 4;
  const int wm = (wv_ >> 1) * 64, wn = (wv_ & 1) * 64;

  const int srow = t >> 2;
  const int ssw = ((t >> 2) & 3) ^ ((t >> 4) & 3);
  const int scol = ((t & 3) ^ ssw) * 8;
  char* ldsA = (char*)sA;
  char* ldsB = (char*)sB;
  const int ldsoff = wv_ * 1024;

  const int swl = (lr & 3) ^ ((lr >> 2) & 3);
  const int rds = (lg ^ swl) * 8;

  f32x4 acc[4][4] = {};

  for (int kt = 0; kt < Kdim / 32; ++kt) {
    const int k0 = kt * 32;
    __syncthreads();
    {
      int r1 = m0 + srow;       if (r1 > M - 1) r1 = M - 1;
      int r2 = m0 + 64 + srow;  if (r2 > M - 1) r2 = M - 1;
      gload_lds16(A + (size_t)r1 * Kdim + k0 + scol, ldsA + 0    + ldsoff);
      gload_lds16(A + (size_t)r2 * Kdim + k0 + scol, ldsA + 4096 + ldsoff);
      gload_lds16(B + (size_t)(n0 + srow) * Kdim + k0 + scol,      ldsB + 0    + ldsoff);
      gload_lds16(B + (size_t)(n0 + 64 + srow) * Kdim + k0 + scol, ldsB + 4096 + ldsoff);
    }
    __syncthreads();
    bf16x8 af[4], bfr[4];
#pragma unroll
    for (int mt = 0; mt < 4; ++mt)
      af[mt] = *(const bf16x8*)&sA[(wm + mt * 16 + lr) * 32 + rds];
#pragma unroll
    for (int nt = 0; nt < 4; ++nt)
      bfr[nt] = *(const bf16x8*)&sB[(wn + nt * 16 + lr) * 32 + rds];
#pragma unroll
    for (int mt = 0; mt < 4; ++mt)
#pragma unroll
      for (int nt = 0; nt < 4; ++nt)
        acc[mt][nt] = __builtin_amdgcn_mfma_f32_16x16x32_bf16(af[mt], bfr[nt], acc[mt][nt], 0, 0, 0);
  }

#pragma unroll
  for (int mt = 0; mt < 4; ++mt) {
#pragma unroll
    for (int nt = 0; nt < 4; ++nt) {
      const int gc = n0 + wn + nt * 16 + lr;
      const float bb2 = bias[gc];
#pragma unroll
      for (int r = 0; r < 4; ++r) {
        const int gr = m0 + wm + mt * 16 + lg * 4 + r;
        const float v = acc[mt][nt][r] + bb2;
        if (gr < M) {
          int bI = gr / 77, s = gr - bI * 77;
          int hh = gc >> 6, d = gc & 63;
          if (!half)
            outp[(((size_t)bI * 16 + hh) * 96 + s) * 64 + d] = f2bf(v);
          else
            outp[(((size_t)bI * 16 + hh) * 64 + d) * 96 + s] = f2bf(v);
        }
      }
    }
  }
}

// ---------------- big GEMM (r11 loop) + FUSED ATTENTION epilogue (EPI 0) ----------------
// Main loop identical to r11 (passing, 183us): 256x256, BK=32, 4-slot LDS ring,
// reg-dbuf read prefetch, vmcnt(8) ledger, XCD swizzle.
// EPI 0 (Q-projection): block tile = 1 batch x 4 complete heads; wave (wm,wn) owns
// 128 q-rows x head hh=(n0>>6)+wn. After the K-loop the LDS ring is dead ->
// per-wave 16KB scratch: Qs[32][72], Ps[32][104]. Per 32-row chunk (4 chunks,
// fully unrolled for static acc indexing): bias+cvt -> Qs -> A-frags; QK^T with
// K-frags read DIRECT FROM GLOBAL KT (L2-resident, same addressing as old k_attn);
// 16-lane-shuffle softmax (proven); P -> Ps; PV with global VT; attn-out -> QB.
// Eliminates the separate k_attn kernel + 256MB of QB round-trip traffic.
// EPI 1 (out-proj): standard +bias f32 epilogue.
template <int EPI>
__global__ __launch_bounds__(512, 2) void gemm256(
    const u16* __restrict__ A, const u16* __restrict__ Bp,
    const float* __restrict__ bias, void* __restrict__ outp,
    const u16* __restrict__ KT, const u16* __restrict__ VT)
{
  __shared__ char lds[131072];
  const int t = threadIdx.x;
  const int cpx = (int)gridDim.x >> 3;
  const int swz = ((int)blockIdx.x & 7) * cpx + ((int)blockIdx.x >> 3);
  const int bm = swz >> 2, bn = swz & 3;
  const int m0 = bm * 256, n0 = bn * 256;
  const int w = t >> 6, l = t & 63, lr = l & 15, lg = l >> 4;
  const int wm = w >> 2, wn = w & 3;   // 2 M-waves x 4 N-waves, wave tile 128x64

  const int srow = t >> 2;
  const int scol = ((t & 3) ^ ((t >> 2) & 3) ^ ((t >> 4) & 3)) * 8;  // elems
  const int rsw = (lg ^ (lr & 3) ^ ((lr >> 2) & 3)) << 4;            // bytes
  const int arow = wm * 128 + lr;
  const int brow = wn * 64 + lr;

  f32x4 acc[8][4] = {};

#define RD(dstA, dstB, sbb) { \
  _Pragma("unroll") for (int q = 0; q < 8; ++q) \
    dstA[q] = *(const bf16x8*)(lds + (sbb) + ((arow + q * 16) << 6) + rsw); \
  _Pragma("unroll") for (int nt = 0; nt < 4; ++nt) \
    dstB[nt] = *(const bf16x8*)(lds + (sbb) + 16384 + ((brow + nt * 16) << 6) + rsw); }
#define STAGE(kt, sbb) { \
    gload_lds16(A  + (size_t)(m0 + srow) * 1024 + (kt) * 32 + scol,       lds + (sbb) + t * 16); \
    gload_lds16(A  + (size_t)(m0 + 128 + srow) * 1024 + (kt) * 32 + scol, lds + (sbb) + 8192 + t * 16); \
    gload_lds16(Bp + (size_t)(n0 + srow) * 1024 + (kt) * 32 + scol,       lds + (sbb) + 16384 + t * 16); \
    gload_lds16(Bp + (size_t)(n0 + 128 + srow) * 1024 + (kt) * 32 + scol, lds + (sbb) + 24576 + t * 16); }
#define MM(a_, b_) { __builtin_amdgcn_s_setprio(1); \
  _Pragma("unroll") for (int q = 0; q < 8; ++q) \
    _Pragma("unroll") for (int nt = 0; nt < 4; ++nt) \
      acc[q][nt] = __builtin_amdgcn_mfma_f32_16x16x32_bf16(a_[q], b_[nt], acc[q][nt], 0, 0, 0); \
  __builtin_amdgcn_s_setprio(0); }
#define BAR __builtin_amdgcn_s_barrier()
#define SB0 __builtin_amdgcn_sched_barrier(0)
#define VM8 asm volatile("s_waitcnt vmcnt(8)" ::: "memory")

  bf16x8 aA[8], bA[4], aB[8], bB[4];

  // prologue: stage tiles 0,1,2 into slots 0,1,2; vmcnt(8) retires tile 0; read it.
  STAGE(0, 0); STAGE(1, 32768); STAGE(2, 65536);
  VM8; SB0; BAR;
  RD(aA, bA, 0);

  int rdo = 32768, sto = 98304;
#pragma unroll 1
  for (int tt = 0; tt < 32; tt += 2) {
    { // body A: consume tile tt (aA/bA), prefetch-read tile tt+1 into aB/bB
      int ks = tt + 3; if (ks > 31) ks = 31;
      STAGE(ks, sto); sto = (sto + 32768) & 131071;
      VM8; SB0; BAR;
      RD(aB, bB, rdo); rdo = (rdo + 32768) & 131071;
      MM(aA, bA);
      BAR;
    }
    { // body B: consume tile tt+1 (aB/bB), prefetch-read tile tt+2 into aA/bA
      int ks = tt + 4; if (ks > 31) ks = 31;
      STAGE(ks, sto); sto = (sto + 32768) & 131071;
      VM8; SB0; BAR;
      RD(aA, bA, rdo); rdo = (rdo + 32768) & 131071;
      MM(aB, bB);
      BAR;
    }
  }
  asm volatile("s_waitcnt vmcnt(0)" ::: "memory");  // drain dummy stages
  SB0; BAR;                                          // ring quiescent block-wide

#undef RD
#undef STAGE
#undef MM
#undef BAR
#undef SB0
#undef VM8

  if constexpr (EPI == 1) {
    // out-proj epilogue: +bias -> f32
#pragma unroll
    for (int q = 0; q < 8; ++q) {
#pragma unroll
      for (int nt = 0; nt < 4; ++nt) {
        const int gc = n0 + wn * 64 + nt * 16 + lr;
        const float bb = bias[gc];
#pragma unroll
        for (int r = 0; r < 4; ++r) {
          const int gr = m0 + wm * 128 + q * 16 + lg * 4 + r;
          ((float*)outp)[(size_t)gr * 1024 + gc] = acc[q][nt][r] + bb;
        }
      }
    }
  } else {
    // ---- fused attention epilogue ----
    const int hh = (n0 >> 6) + wn;          // head for this wave (64 cols = 1 head)
    const int b = m0 >> 12;                 // batch (256 rows never straddle)
    const u16* gK = KT + (size_t)(b * 16 + hh) * (96 * 64);
    const u16* gV = VT + (size_t)(b * 16 + hh) * (64 * 96);
    u16* Qs = (u16*)(lds + w * 16384);          // [32][72]
    u16* Ps = (u16*)(lds + w * 16384 + 8192);   // [32][104]
    u16* QBo = (u16*)outp;

    float bb[4];
#pragma unroll
    for (int nt = 0; nt < 4; ++nt) bb[nt] = bias[n0 + wn * 64 + nt * 16 + lr];

#pragma unroll
    for (int cc = 0; cc < 4; ++cc) {
      // 1. bias + cvt + write Q chunk (rows cc*32..+31) to wave-private LDS
#pragma unroll
      for (int qq = 0; qq < 2; ++qq)
#pragma unroll
        for (int nt = 0; nt < 4; ++nt)
#pragma unroll
          for (int r = 0; r < 4; ++r)
            Qs[(qq * 16 + lg * 4 + r) * 72 + nt * 16 + lr] =
                f2bf(acc[cc * 2 + qq][nt][r] + bb[nt]);

      // 2. Q A-frags (same-wave LDS RAW -> compiler lgkmcnt)
      bf16x8 aq[2][2];
#pragma unroll
      for (int qq = 0; qq < 2; ++qq)
#pragma unroll
        for (int ks = 0; ks < 2; ++ks)
          aq[qq][ks] = *(const bf16x8*)&Qs[(qq * 16 + lr) * 72 + ks * 32 + lg * 8];

      // 3. scores QK^T: K frags direct from global (L2-resident)
      f32x4 s_[2][5] = {};
#pragma unroll
      for (int nt = 0; nt < 5; ++nt) {
#pragma unroll
        for (int ks = 0; ks < 2; ++ks) {
          bf16x8 bk = *(const bf16x8*)&gK[(nt * 16 + lr) * 64 + ks * 32 + lg * 8];
#pragma unroll
          for (int qq = 0; qq < 2; ++qq)
            s_[qq][nt] = __builtin_amdgcn_mfma_f32_16x16x32_bf16(aq[qq][ks], bk, s_[qq][nt], 0, 0, 0);
        }
      }
#pragma unroll
      for (int qq = 0; qq < 2; ++qq)
#pragma unroll
        for (int nt = 0; nt < 5; ++nt)
#pragma unroll
          for (int r = 0; r < 4; ++r)
            s_[qq][nt][r] *= 0.125f;
      if (lr >= 13) {
#pragma unroll
        for (int qq = 0; qq < 2; ++qq)
#pragma unroll
          for (int r = 0; r < 4; ++r)
            s_[qq][4][r] = -1e30f;
      }

      // 4. softmax per row (reduce across 16 lanes lr)
      float ri[2][4];
#pragma unroll
      for (int qq = 0; qq < 2; ++qq) {
#pragma unroll
        for (int r = 0; r < 4; ++r) {
          float m1 = s_[qq][0][r];
#pragma unroll
          for (int nt = 1; nt < 5; ++nt) m1 = fmaxf(m1, s_[qq][nt][r]);
          m1 = fmaxf(m1, __shfl_xor(m1, 1, 64));
          m1 = fmaxf(m1, __shfl_xor(m1, 2, 64));
          m1 = fmaxf(m1, __shfl_xor(m1, 4, 64));
          m1 = fmaxf(m1, __shfl_xor(m1, 8, 64));
          float s1 = 0.f;
#pragma unroll
          for (int nt = 0; nt < 5; ++nt) {
            float e = __expf(s_[qq][nt][r] - m1);
            s_[qq][nt][r] = e;
            s1 += e;
          }
          s1 += __shfl_xor(s1, 1, 64);
          s1 += __shfl_xor(s1, 2, 64);
          s1 += __shfl_xor(s1, 4, 64);
          s1 += __shfl_xor(s1, 8, 64);
          ri[qq][r] = 1.0f / s1;
        }
      }

      // 5. P -> LDS (+ zero pad keys 80..95)
#pragma unroll
      for (int qq = 0; qq < 2; ++qq)
#pragma unroll
        for (int nt = 0; nt < 5; ++nt)
#pragma unroll
          for (int r = 0; r < 4; ++r)
            Ps[(qq * 16 + lg * 4 + r) * 104 + nt * 16 + lr] = f2bf(s_[qq][nt][r] * ri[qq][r]);
#pragma unroll
      for (int qq = 0; qq < 2; ++qq)
#pragma unroll
        for (int r = 0; r < 4; ++r)
          Ps[(qq * 16 + lg * 4 + r) * 104 + 80 + lr] = 0;

      // 6. PV: V frags direct from global VT [d][s]
      f32x4 o_[2][4] = {};
#pragma unroll
      for (int ks = 0; ks < 3; ++ks) {
        bf16x8 ap[2];
#pragma unroll
        for (int qq = 0; qq < 2; ++qq)
          ap[qq] = *(const bf16x8*)&Ps[(qq * 16 + lr) * 104 + ks * 32 + lg * 8];
#pragma unroll
        for (int nt = 0; nt < 4; ++nt) {
          bf16x8 bv = *(const bf16x8*)&gV[(nt * 16 + lr) * 96 + ks * 32 + lg * 8];
#pragma unroll
          for (int qq = 0; qq < 2; ++qq)
            o_[qq][nt] = __builtin_amdgcn_mfma_f32_16x16x32_bf16(ap[qq], bv, o_[qq][nt], 0, 0, 0);
        }
      }

      // 7. attn-out -> QB
#pragma unroll
      for (int qq = 0; qq < 2; ++qq)
#pragma unroll
        for (int nt = 0; nt < 4; ++nt)
#pragma unroll
          for (int r = 0; r < 4; ++r)
            QBo[(size_t)(m0 + wm * 128 + cc * 32 + qq * 16 + lg * 4 + r) * 1024
                + hh * 64 + nt * 16 + lr] = f2bf(o_[qq][nt][r]);
    }
  }
}

// ---------------- launch ----------------

extern "C" void kernel_launch(void* const* d_in, const int* in_sizes, int n_in,
                              void* d_out, int out_size, void* d_ws, size_t ws_size,
                              hipStream_t stream) {
  const float* x  = (const float*)d_in[0];
  const float* y  = (const float*)d_in[1];
  const float* wq = (const float*)d_in[2];
  const float* bq = (const float*)d_in[3];
  const float* wk = (const float*)d_in[4];
  const float* bk = (const float*)d_in[5];
  const float* wv = (const float*)d_in[6];
  const float* bv = (const float*)d_in[7];
  const float* wo = (const float*)d_in[8];
  const float* bo = (const float*)d_in[9];

  char* ws = (char*)d_ws;
  u16* QB   = (u16*)(ws + 0);            // 65536x1024 bf16 = 128 MB (attn-out)
  u16* WQ1T = (u16*)(ws + 134217728);    // [1024][1024] bf16, 2 MB
  u16* WO1T = (u16*)(ws + 136314880);    // 2 MB
  u16* WK1T = (u16*)(ws + 138412032);    // [1024][768] bf16, 1.5 MB
  u16* WV1T = (u16*)(ws + 139984896);    // 1.5 MB
  u16* YB   = (u16*)(ws + 141557760);    // [1232][768] bf16, 1.85 MB
  u16* KT   = (u16*)(ws + 143654912);    // [16][16][96][64] bf16, 3 MB
  u16* VT   = (u16*)(ws + 146800640);    // [16][16][64][96] bf16, 3 MB

  u16*   XB  = (u16*)d_out;   // x as bf16, first 128 MB of d_out (consumed before final write)
  float* OUT = (float*)d_out;

  // prep
  k_zero<<<768, 256, 0, stream>>>((u16x8*)KT, 393216);          // zero KT+VT (adjacent, 6 MB)
  k_cvt_x<<<4096, 256, 0, stream>>>(x, XB, 16777216);
  k_prep_wt<<<896, 256, 0, stream>>>(wq, wo, wk, wv, WQ1T, WO1T, WK1T, WV1T);
  k_prep_y<<<924, 256, 0, stream>>>(y, YB, 236544);

  // K+V projections (one launch): M=1232, K=768
  k_gemm_kv<<<160, 256, 0, stream>>>(YB, WK1T, bk, KT, WV1T, bv, VT);

  // Q projection + FUSED ATTENTION -> QB (attn output)
  gemm256<0><<<1024, 512, 0, stream>>>(XB, WQ1T, bq, QB, KT, VT);

  // output projection -> f32 d_out
  gemm256<1><<<1024, 512, 0, stream>>>(QB, WO1T, bo, OUT, nullptr, nullptr);
}